// Round 1
// 131.220 us; speedup vs baseline: 1.0118x; 1.0118x over previous
//
#include <hip/hip_runtime.h>
#include <math.h>

#define BS 8
#define NPTS 16384
#define C 32
#define K 256
#define KNNK 16
#define NBINS 512
#define BINW 0.00025f
#define CAP 4096
#define NSPL 64          // point-splits per graph in k_logits

typedef float f32x4 __attribute__((ext_vector_type(4)));
typedef __bf16 bf16x8 __attribute__((ext_vector_type(8)));
union U16x8 { int4 i; bf16x8 v; unsigned short u[8]; };

// ---------------------------------------------------------------------------
// Phase 1: MFMA logit GEMM + exp + weighted position accumulation.
// Split-bf16: L = A_lo*B_hi + A_hi*B_lo + A_hi*B_hi (fp32 MFMA accum);
// verified round 5: identical KNN sets vs fp32 path (same absmax).
// Pooling head (W_pool) unused: its logit term is constant over n and cancels
// in the per-graph softmax. Block = 256 thr (4 waves) x 256-pt chunk; wave
// (h=w&1) takes kp-half, (nh=w>>1) takes n-half. B-frags loaded directly from
// fp32 Wr (L2-resident, once per block) and split in-regs. Merge via plain
// per-block partial stores.
// ---------------------------------------------------------------------------
__global__ __launch_bounds__(256, 2) void k_logits(
    const float* __restrict__ f, const float* __restrict__ pos,
    const float* __restrict__ Wr, float* __restrict__ partials) {
  int b = blockIdx.x >> 6;          // 64 blocks per graph
  int r = blockIdx.x & 63;
  int pbase = b * NPTS + r * 256;
  int t = threadIdx.x;
  int w = t >> 6, lane = t & 63;
  int h = w & 1, nh = w >> 1;
  int quad = lane >> 4, col = lane & 15;

  __shared__ float4 posLDS[256];
  __shared__ float4 fm[2][256];

  // stage pos chunk (256 pts x 12 B) -> padded float4 via LDS repack
  float* rawf = (float*)&fm[0][0];
  if (t < 192) ((float4*)rawf)[t] = ((const float4*)(pos + (size_t)pbase * 3))[t];
  __syncthreads();
  float4 myp = make_float4(rawf[t * 3], rawf[t * 3 + 1], rawf[t * 3 + 2], 0.f);
  __syncthreads();
  posLDS[t] = myp;

  // B fragments for this wave's kp-half (8 tiles), direct fp32 load + split.
  // B[k=quad*8+j][n=tile*16+col] = Wr[(quad*8+j)*K + tile*16+col]
  U16x8 Bh[8], Bl[8];
#pragma unroll
  for (int jt = 0; jt < 8; jt++) {
    int tile = h * 8 + jt;
#pragma unroll
    for (int j = 0; j < 8; j++) {
      float v = Wr[(quad * 8 + j) * K + tile * 16 + col];
      unsigned u = __float_as_uint(v);
      unsigned hb = u >> 16;
      float hf = __uint_as_float(hb << 16);
      unsigned lb = __float_as_uint(v - hf) >> 16;
      Bh[jt].u[j] = (unsigned short)hb;
      Bl[jt].u[j] = (unsigned short)lb;
    }
  }
  float acce[8], accx[8], accy[8], accz[8];
#pragma unroll
  for (int jt = 0; jt < 8; jt++) { acce[jt] = 0.f; accx[jt] = 0.f; accy[jt] = 0.f; accz[jt] = 0.f; }

#pragma unroll 1
  for (int nt = nh * 8; nt < nh * 8 + 8; nt++) {
    // A fragment: lane holds A[m=col][k=quad*8+j] = f[pt][ch], fp32 -> hi/lo
    const float* fb = f + ((size_t)(pbase + nt * 16 + col)) * C + quad * 8;
    float4 a0 = *(const float4*)fb;
    float4 a1 = *(const float4*)(fb + 4);
    float av[8] = {a0.x, a0.y, a0.z, a0.w, a1.x, a1.y, a1.z, a1.w};
    U16x8 Ah, Al;
#pragma unroll
    for (int j = 0; j < 8; j++) {
      unsigned u = __float_as_uint(av[j]);
      unsigned hb = u >> 16;
      float hf = __uint_as_float(hb << 16);
      unsigned lb = __float_as_uint(av[j] - hf) >> 16;
      Ah.u[j] = (unsigned short)hb;
      Al.u[j] = (unsigned short)lb;
    }
    float4 pr0 = posLDS[nt * 16 + quad * 4 + 0];
    float4 pr1 = posLDS[nt * 16 + quad * 4 + 1];
    float4 pr2 = posLDS[nt * 16 + quad * 4 + 2];
    float4 pr3 = posLDS[nt * 16 + quad * 4 + 3];
#pragma unroll
    for (int jt = 0; jt < 8; jt++) {
      f32x4 d = {0.f, 0.f, 0.f, 0.f};
      d = __builtin_amdgcn_mfma_f32_16x16x32_bf16(Al.v, Bh[jt].v, d, 0, 0, 0);
      d = __builtin_amdgcn_mfma_f32_16x16x32_bf16(Ah.v, Bl[jt].v, d, 0, 0, 0);
      d = __builtin_amdgcn_mfma_f32_16x16x32_bf16(Ah.v, Bh[jt].v, d, 0, 0, 0);
      // C/D layout: col=lane&15 (kp), row=quad*4+reg (pt)  [m89-verified]
      float e0 = __expf(d[0]), e1 = __expf(d[1]), e2 = __expf(d[2]), e3 = __expf(d[3]);
      acce[jt] += (e0 + e1) + (e2 + e3);
      accx[jt] += e0 * pr0.x + e1 * pr1.x + e2 * pr2.x + e3 * pr3.x;
      accy[jt] += e0 * pr0.y + e1 * pr1.y + e2 * pr2.y + e3 * pr3.y;
      accz[jt] += e0 * pr0.z + e1 * pr1.z + e2 * pr2.z + e3 * pr3.z;
    }
  }

  // reduce across quads (lane bits 4,5); kp slot = h*128 + jt*16 + (lane&15)
#pragma unroll
  for (int jt = 0; jt < 8; jt++) {
    acce[jt] += __shfl_xor(acce[jt], 16); acce[jt] += __shfl_xor(acce[jt], 32);
    accx[jt] += __shfl_xor(accx[jt], 16); accx[jt] += __shfl_xor(accx[jt], 32);
    accy[jt] += __shfl_xor(accy[jt], 16); accy[jt] += __shfl_xor(accy[jt], 32);
    accz[jt] += __shfl_xor(accz[jt], 16); accz[jt] += __shfl_xor(accz[jt], 32);
  }
  __syncthreads();   // fm[0] was aliased as pos staging; all reads done
  if (lane < 16) {
#pragma unroll
    for (int jt = 0; jt < 8; jt++)
      fm[nh][h * 128 + jt * 16 + lane] = make_float4(acce[jt], accx[jt], accy[jt], accz[jt]);
  }
  __syncthreads();
  float4 v0 = fm[0][t], v1 = fm[1][t];
  float4* po = (float4*)partials;
  po[(size_t)blockIdx.x * 256 + t] =
      make_float4(v0.x + v1.x, v0.y + v1.y, v0.z + v1.z, v0.w + v1.w);
}

// ---------------------------------------------------------------------------
// Phase 2a (k_merge, grid=BS, 1024 thr): merge 64 split-partials -> keypoints,
// centroid + max keypoint-centroid distance. Also zeroes the global hist +
// candidate counter for the downstream kernels (stream-ordered).
// ---------------------------------------------------------------------------
__global__ __launch_bounds__(1024) void k_merge(
    const float* __restrict__ partials, float* __restrict__ kpts,
    float* __restrict__ gstat, unsigned* __restrict__ ghist,
    unsigned* __restrict__ ccnt) {
  int b = blockIdx.x;
  int t = threadIdx.x;
  int lane = t & 63, wave = t >> 6;

  __shared__ float4 mred[4][256];
  __shared__ float kxs[256], kys[256], kzs[256];
  __shared__ float wred[16][3];
  __shared__ float bc[4];

  if (t < NBINS) ghist[b * NBINS + t] = 0;
  if (t == 0) ccnt[b] = 0;

  // --- merge partials (4-way split-sum, fully unrolled for MLP) ---
  {
    int kp = t & 255, q = t >> 8;   // q in 0..3, 16 splits each
    const float4* po = (const float4*)partials;
    float sl = 0.f, sx = 0.f, sy = 0.f, sz = 0.f;
#pragma unroll
    for (int j = 0; j < 16; j++) {
      float4 v = po[((size_t)(b * NSPL + q * 16 + j)) * 256 + kp];
      sl += v.x; sx += v.y; sy += v.z; sz += v.w;
    }
    mred[q][kp] = make_float4(sl, sx, sy, sz);
  }
  __syncthreads();
  if (t < 256) {
    float4 a0 = mred[0][t], a1 = mred[1][t], a2 = mred[2][t], a3 = mred[3][t];
    float L = (a0.x + a1.x) + (a2.x + a3.x);
    float inv = 1.f / L;
    float x = ((a0.y + a1.y) + (a2.y + a3.y)) * inv;
    float y = ((a0.z + a1.z) + (a2.z + a3.z)) * inv;
    float z = ((a0.w + a1.w) + (a2.w + a3.w)) * inv;
    kxs[t] = x; kys[t] = y; kzs[t] = z;
    ((float4*)kpts)[b * 256 + t] = make_float4(x, y, z, 0.f);
  }
  __syncthreads();

  // --- centroid ---
  float sx = 0.f, sy = 0.f, sz = 0.f;
  if (t < 256) { sx = kxs[t]; sy = kys[t]; sz = kzs[t]; }
#pragma unroll
  for (int off = 32; off; off >>= 1) {
    sx += __shfl_xor(sx, off, 64);
    sy += __shfl_xor(sy, off, 64);
    sz += __shfl_xor(sz, off, 64);
  }
  if (lane == 0) { wred[wave][0] = sx; wred[wave][1] = sy; wred[wave][2] = sz; }
  __syncthreads();
  if (t == 0) {
    float X = 0.f, Y = 0.f, Z = 0.f;
#pragma unroll
    for (int i = 0; i < 16; i++) { X += wred[i][0]; Y += wred[i][1]; Z += wred[i][2]; }
    bc[0] = X / K; bc[1] = Y / K; bc[2] = Z / K;
  }
  __syncthreads();
  float cx = bc[0], cy = bc[1], cz = bc[2];

  // --- max keypoint distance from centroid ---
  float md = 0.f;
  if (t < 256) {
    float dx = kxs[t] - cx, dy = kys[t] - cy, dz = kzs[t] - cz;
    md = dx * dx + dy * dy + dz * dz;
  }
#pragma unroll
  for (int off = 32; off; off >>= 1) md = fmaxf(md, __shfl_xor(md, off, 64));
  if (lane == 0) wred[wave][0] = md;
  __syncthreads();
  if (t == 0) {
    float m = 0.f;
#pragma unroll
    for (int i = 0; i < 16; i++) m = fmaxf(m, wred[i][0]);
    ((float4*)gstat)[b] = make_float4(cx, cy, cz, sqrtf(m));
  }
}

// ---------------------------------------------------------------------------
// Phase 2b (k_hist, grid=BS*8, 256 thr, 8 pts/thr): per-block LDS histogram of
// d2(point, centroid), catch-all bin skipped; sparse merge into global hist.
// ---------------------------------------------------------------------------
__global__ __launch_bounds__(256) void k_hist(
    const float* __restrict__ pos, const float* __restrict__ gstat,
    unsigned* __restrict__ ghist) {
  int b = blockIdx.x >> 3;          // 8 chunks per graph
  int ch = blockIdx.x & 7;
  int t = threadIdx.x;
  __shared__ unsigned hist[NBINS];
  hist[t] = 0; hist[t + 256] = 0;
  float4 st = ((const float4*)gstat)[b];
  __syncthreads();
  int base = b * NPTS + ch * 2048;
#pragma unroll
  for (int i = 0; i < 8; i++) {
    int p = base + i * 256 + t;
    float dx = pos[p * 3 + 0] - st.x, dy = pos[p * 3 + 1] - st.y, dz = pos[p * 3 + 2] - st.z;
    float d2 = dx * dx + dy * dy + dz * dz;
    int bin = (int)(d2 * (1.0f / BINW));
    if (bin < NBINS - 1) atomicAdd(&hist[bin], 1u);
  }
  __syncthreads();
  unsigned v0 = hist[t], v1 = hist[t + 256];
  if (v0) atomicAdd(&ghist[b * NBINS + t], v0);
  if (v1) atomicAdd(&ghist[b * NBINS + t + 256], v1);
}

// ---------------------------------------------------------------------------
// Phase 2c (k_compact, grid=BS*8, 256 thr): radius from global hist
// (T >= d16(centroid); R = T + 2*maxdiam, triangle-ineq exact; no-T2 ->
// R=inf -> overflow -> k_topk global-scan fallback), then compact candidates
// into a global per-graph buffer.
// ---------------------------------------------------------------------------
__global__ __launch_bounds__(256) void k_compact(
    const float* __restrict__ pos, const float* __restrict__ gstat,
    const unsigned* __restrict__ ghist, unsigned* __restrict__ ccnt,
    float4* __restrict__ cand) {
  int b = blockIdx.x >> 3;
  int ch = blockIdx.x & 7;
  int t = threadIdx.x;
  __shared__ unsigned hist[NBINS];
  __shared__ float shr2;
  hist[t] = ghist[b * NBINS + t];
  hist[t + 256] = ghist[b * NBINS + t + 256];
  float4 st = ((const float4*)gstat)[b];
  __syncthreads();
  if (t == 0) {
    unsigned cum = 0; float T2 = -1.f;
    for (int i = 0; i < NBINS - 1; i++) {
      cum += hist[i];
      if (cum >= KNNK) { T2 = (i + 1) * BINW; break; }
    }
    if (T2 < 0.f) shr2 = 3.0e38f;
    else {
      float Rf = sqrtf(T2) + 2.f * st.w;
      shr2 = Rf * Rf;
    }
  }
  __syncthreads();
  float r2 = shr2;
#pragma unroll
  for (int i = 0; i < 8; i++) {
    int pl = ch * 2048 + i * 256 + t;
    int p = b * NPTS + pl;
    float px = pos[p * 3 + 0], py = pos[p * 3 + 1], pz = pos[p * 3 + 2];
    float dx = px - st.x, dy = py - st.y, dz = pz - st.z;
    float d2 = dx * dx + dy * dy + dz * dz;
    if (d2 <= r2) {
      unsigned u = atomicAdd(&ccnt[b], 1u);
      if (u < CAP) cand[(size_t)b * CAP + u] = make_float4(px, py, pz, __int_as_float(pl));
    }
  }
}

// ---------------------------------------------------------------------------
// Phase 2d (k_topk, grid=BS, 256 thr): exact top-16 per keypoint over the
// LDS-resident candidate set (~40/graph); overflow -> full global scan.
// ---------------------------------------------------------------------------
__global__ __launch_bounds__(256) void k_topk(
    const float* __restrict__ pos, const float* __restrict__ kpts,
    const unsigned* __restrict__ ccnt, const float4* __restrict__ cand,
    int* __restrict__ knn) {
  int b = blockIdx.x;
  int t = threadIdx.x;
  __shared__ float cxs[CAP], cys[CAP], czs[CAP];
  __shared__ int cis[CAP];

  unsigned cnt = ccnt[b];
  int ovf = cnt > CAP;
  int n = ovf ? 0 : (int)cnt;
  for (int j = t; j < n; j += 256) {
    float4 v = cand[(size_t)b * CAP + j];
    cxs[j] = v.x; cys[j] = v.y; czs[j] = v.z; cis[j] = __float_as_int(v.w);
  }
  __syncthreads();

  float4 kpt = ((const float4*)kpts)[b * 256 + t];
  float kx = kpt.x, ky = kpt.y, kz = kpt.z;
  float dd[KNNK]; int ii[KNNK];
#pragma unroll
  for (int j = 0; j < KNNK; j++) { dd[j] = 1e30f; ii[j] = 0; }
  float mx = 1e30f;
  if (!ovf) {
    for (int j = 0; j < n; j++) {
      float dx = kx - cxs[j], dy = ky - cys[j], dz = kz - czs[j];
      float d2 = dx * dx + dy * dy + dz * dz;
      if (d2 < mx) {
        int sm = 0; float bv = dd[0];
#pragma unroll
        for (int s = 1; s < KNNK; s++) if (dd[s] > bv) { bv = dd[s]; sm = s; }
#pragma unroll
        for (int s = 0; s < KNNK; s++) if (s == sm) { dd[s] = d2; ii[s] = cis[j]; }
        mx = dd[0];
#pragma unroll
        for (int s = 1; s < KNNK; s++) mx = fmaxf(mx, dd[s]);
      }
    }
  } else {
    for (int j = 0; j < NPTS; j++) {
      const float* pp = pos + (size_t)(b * NPTS + j) * 3;
      float dx = kx - pp[0], dy = ky - pp[1], dz = kz - pp[2];
      float d2 = dx * dx + dy * dy + dz * dz;
      if (d2 < mx) {
        int sm = 0; float bv = dd[0];
#pragma unroll
        for (int s = 1; s < KNNK; s++) if (dd[s] > bv) { bv = dd[s]; sm = s; }
#pragma unroll
        for (int s = 0; s < KNNK; s++) if (s == sm) { dd[s] = d2; ii[s] = j; }
        mx = dd[0];
#pragma unroll
        for (int s = 1; s < KNNK; s++) mx = fmaxf(mx, dd[s]);
      }
    }
  }
  for (int j = 0; j < KNNK; j++) knn[((size_t)(b * K + t)) * KNNK + j] = ii[j];
}

// ---------------------------------------------------------------------------
// Phase 3: gather 16 neighbor feature rows, mean, 32x32 linear.
// ---------------------------------------------------------------------------
__global__ __launch_bounds__(256) void k_extract(
    const float* __restrict__ f, const int* __restrict__ knn,
    const float* __restrict__ We, float* __restrict__ out) {
  __shared__ float P[8][C + 1];
  int tid = threadIdx.x;
  int kp = tid >> 5, c = tid & 31;
  int gk = blockIdx.x * 8 + kp;   // 0..2047
  int b = gk >> 8;
  float s = 0.f;
#pragma unroll
  for (int j = 0; j < KNNK; j++) {
    int pl = knn[(size_t)gk * KNNK + j];
    s += f[((size_t)(b * NPTS + pl)) * C + c];
  }
  P[kp][c] = s * (1.f / KNNK);
  __syncthreads();
  float r = 0.f;
#pragma unroll
  for (int cc = 0; cc < C; cc++) r += P[kp][cc] * We[cc * C + c];
  out[(size_t)gk * C + c] = r;
}

extern "C" void kernel_launch(void* const* d_in, const int* in_sizes, int n_in,
                              void* d_out, int out_size, void* d_ws, size_t ws_size,
                              hipStream_t stream) {
  const float* f   = (const float*)d_in[0];
  const float* pos = (const float*)d_in[1];
  // d_in[2] = W_pool: mathematically unused (bias cancels in segment softmax)
  const float* Wr  = (const float*)d_in[3];
  const float* We  = (const float*)d_in[4];
  float* out = (float*)d_out;

  char* ws = (char*)d_ws;
  float*    partials = (float*)(ws + 0);                  // [512][256][4] f32 = 2 MiB
  int*      knn      = (int*)(ws + 2097152);              // [8][256][16] i32 = 128 KiB
  float*    kpts     = (float*)(ws + 2228224);            // [8][256] float4 = 32 KiB
  float*    gstat    = (float*)(ws + 2260992);            // [8] float4 (cx,cy,cz,maxdiam)
  unsigned* ghist    = (unsigned*)(ws + 2261504);         // [8][512] u32 = 16 KiB
  unsigned* ccnt     = (unsigned*)(ws + 2277888);         // [8] u32
  float4*   cand     = (float4*)(ws + 2278016);           // [8][4096] float4 = 512 KiB

  k_logits <<<dim3(BS * NSPL), dim3(256),  0, stream>>>(f, pos, Wr, partials);
  k_merge  <<<dim3(BS),        dim3(1024), 0, stream>>>(partials, kpts, gstat, ghist, ccnt);
  k_hist   <<<dim3(BS * 8),    dim3(256),  0, stream>>>(pos, gstat, ghist);
  k_compact<<<dim3(BS * 8),    dim3(256),  0, stream>>>(pos, gstat, ghist, ccnt, cand);
  k_topk   <<<dim3(BS),        dim3(256),  0, stream>>>(pos, kpts, ccnt, cand, knn);
  k_extract<<<dim3(256),       dim3(256),  0, stream>>>(f, knn, We, out);
}